// Round 1
// baseline (651.594 us; speedup 1.0000x reference)
//
#include <hip/hip_runtime.h>
#include <math.h>

#define D 4096
#define DA 4106   // D + 10 (dim of gru_in / in_W0 row length)

__device__ __forceinline__ float wave_reduce_sum(float v) {
    #pragma unroll
    for (int off = 32; off > 0; off >>= 1) v += __shfl_xor(v, off, 64);
    return v;
}
__device__ __forceinline__ float wave_reduce_max(float v) {
    #pragma unroll
    for (int off = 32; off > 0; off >>= 1) v = fmaxf(v, __shfl_xor(v, off, 64));
    return v;
}

// ---------------------------------------------------------------------------
// K1: softmax(attn) * context  ->  gru_in[0:4096];  prev_agent_feat -> [4096:4106]
// ---------------------------------------------------------------------------
__global__ __launch_bounds__(1024)
void prep_kernel(const float* __restrict__ attn, const float* __restrict__ ctx,
                 const float* __restrict__ paf, float* __restrict__ gin) {
    __shared__ float red[16];
    __shared__ float bmax, bsum;
    int tid = threadIdx.x, wave = tid >> 6, lane = tid & 63;

    float4 a = ((const float4*)attn)[tid];
    float mx = fmaxf(fmaxf(a.x, a.y), fmaxf(a.z, a.w));
    mx = wave_reduce_max(mx);
    if (lane == 0) red[wave] = mx;
    __syncthreads();
    if (tid == 0) {
        float m = red[0];
        #pragma unroll
        for (int k = 1; k < 16; ++k) m = fmaxf(m, red[k]);
        bmax = m;
    }
    __syncthreads();
    mx = bmax;

    float e0 = expf(a.x - mx), e1 = expf(a.y - mx), e2 = expf(a.z - mx), e3 = expf(a.w - mx);
    float s = wave_reduce_sum(e0 + e1 + e2 + e3);
    __syncthreads();              // red reuse barrier
    if (lane == 0) red[wave] = s;
    __syncthreads();
    if (tid == 0) {
        float t = 0.f;
        #pragma unroll
        for (int k = 0; k < 16; ++k) t += red[k];
        bsum = t;
    }
    __syncthreads();
    float inv = 1.f / bsum;

    float4 c = ((const float4*)ctx)[tid];
    float4 o;
    o.x = e0 * inv * c.x; o.y = e1 * inv * c.y; o.z = e2 * inv * c.z; o.w = e3 * inv * c.w;
    ((float4*)gin)[tid] = o;
    if (tid < 10) gin[D + tid] = paf[tid];
}

// ---------------------------------------------------------------------------
// Generic GEMV: y = W @ f(x) + bias, f = identity or LayerNorm+ReLU (stats
// computed redundantly per block — 16 KB L2 read, negligible).
// NC: row length (4096 -> float4 path, 4106 -> float2 path).
// Block 256 thr (4 waves), each wave RPW consecutive rows.
// ---------------------------------------------------------------------------
template<int NC, bool LN_IN, bool RELU_OUT, int RPW>
__global__ __launch_bounds__(256)
void gemv_kernel(const float* __restrict__ W, const float* __restrict__ xin,
                 const float* __restrict__ bias,
                 const float* __restrict__ g, const float* __restrict__ be,
                 float* __restrict__ y) {
    __shared__ float xs[4160];
    __shared__ float red[8];
    int tid = threadIdx.x, wave = tid >> 6, lane = tid & 63;

    if constexpr (LN_IN) {
        // NC == 4096 here
        const float4* x4 = (const float4*)xin;
        float4 vals[4];
        float s1 = 0.f, s2 = 0.f;
        #pragma unroll
        for (int k = 0; k < 4; ++k) {
            float4 v = x4[tid + k * 256];
            vals[k] = v;
            s1 += (v.x + v.y) + (v.z + v.w);
            s2 += (v.x * v.x + v.y * v.y) + (v.z * v.z + v.w * v.w);
        }
        s1 = wave_reduce_sum(s1); s2 = wave_reduce_sum(s2);
        if (lane == 0) { red[wave] = s1; red[4 + wave] = s2; }
        __syncthreads();
        float ts1 = (red[0] + red[1]) + (red[2] + red[3]);
        float ts2 = (red[4] + red[5]) + (red[6] + red[7]);
        float mu = ts1 * (1.f / 4096.f);
        float rstd = rsqrtf(ts2 * (1.f / 4096.f) - mu * mu + 1e-5f);
        #pragma unroll
        for (int k = 0; k < 4; ++k) {
            float4 v = vals[k];
            float4 gg = ((const float4*)g)[tid + k * 256];
            float4 bb = ((const float4*)be)[tid + k * 256];
            float4 o;
            o.x = fmaxf((v.x - mu) * rstd * gg.x + bb.x, 0.f);
            o.y = fmaxf((v.y - mu) * rstd * gg.y + bb.y, 0.f);
            o.z = fmaxf((v.z - mu) * rstd * gg.z + bb.z, 0.f);
            o.w = fmaxf((v.w - mu) * rstd * gg.w + bb.w, 0.f);
            ((float4*)xs)[tid + k * 256] = o;
        }
        __syncthreads();
    } else {
        for (int i = tid; i < (NC >> 1); i += 256)
            ((float2*)xs)[i] = ((const float2*)xin)[i];
        __syncthreads();
    }

    int row0 = (blockIdx.x * 4 + wave) * RPW;
    if constexpr ((NC & 255) == 0) {
        constexpr int NIT = NC >> 8;   // float4 iters (16 for 4096)
        const float4* xs4 = (const float4*)xs;
        for (int rr = 0; rr < RPW; ++rr) {
            int row = row0 + rr;
            const float4* Wr = (const float4*)(W + (size_t)row * NC);
            float ax = 0.f, ay = 0.f, az = 0.f, aw = 0.f;
            #pragma unroll 8
            for (int it = 0; it < NIT; ++it) {
                float4 w = Wr[it * 64 + lane];
                float4 xv = xs4[it * 64 + lane];
                ax += w.x * xv.x; ay += w.y * xv.y; az += w.z * xv.z; aw += w.w * xv.w;
            }
            float s = wave_reduce_sum((ax + ay) + (az + aw));
            if (lane == 0) {
                s += bias[row];
                if (RELU_OUT) s = fmaxf(s, 0.f);
                y[row] = s;
            }
        }
    } else {
        // float2 path (rows only 8B-aligned: NC=4106)
        constexpr int NC2 = NC >> 1;         // 2053 float2
        constexpr int NFULL = NC2 >> 6;      // 32
        const float2* xs2 = (const float2*)xs;
        for (int rr = 0; rr < RPW; ++rr) {
            int row = row0 + rr;
            const float2* Wr = (const float2*)(W + (size_t)row * NC);
            float ax = 0.f, ay = 0.f;
            #pragma unroll 8
            for (int it = 0; it < NFULL; ++it) {
                float2 w = Wr[it * 64 + lane];
                float2 xv = xs2[it * 64 + lane];
                ax += w.x * xv.x; ay += w.y * xv.y;
            }
            int idx = (NFULL << 6) + lane;
            if (idx < NC2) {
                float2 w = Wr[idx];
                float2 xv = xs2[idx];
                ax += w.x * xv.x; ay += w.y * xv.y;
            }
            float s = wave_reduce_sum(ax + ay);
            if (lane == 0) {
                s += bias[row];
                if (RELU_OUT) s = fmaxf(s, 0.f);
                y[row] = s;
            }
        }
    }
}

// ---------------------------------------------------------------------------
// K5: fused GRU GEMVs — wave computes row r of (Wih @ xa) and (Whh @ xb).
// ---------------------------------------------------------------------------
template<int RPW>
__global__ __launch_bounds__(256)
void gru_gemv_kernel(const float* __restrict__ Wih, const float* __restrict__ Whh,
                     const float* __restrict__ xa, const float* __restrict__ xb,
                     const float* __restrict__ bih, const float* __restrict__ bhh,
                     float* __restrict__ gi, float* __restrict__ gh) {
    __shared__ float xsa[D], xsb[D];
    int tid = threadIdx.x, wave = tid >> 6, lane = tid & 63;
    for (int i = tid; i < 1024; i += 256) {
        ((float4*)xsa)[i] = ((const float4*)xa)[i];
        ((float4*)xsb)[i] = ((const float4*)xb)[i];
    }
    __syncthreads();

    const float4* xa4 = (const float4*)xsa;
    const float4* xb4 = (const float4*)xsb;
    int row0 = (blockIdx.x * 4 + wave) * RPW;
    for (int rr = 0; rr < RPW; ++rr) {
        int row = row0 + rr;
        {
            const float4* Wr = (const float4*)(Wih + (size_t)row * D);
            float ax = 0.f, ay = 0.f, az = 0.f, aw = 0.f;
            #pragma unroll 8
            for (int it = 0; it < 16; ++it) {
                float4 w = Wr[it * 64 + lane];
                float4 xv = xa4[it * 64 + lane];
                ax += w.x * xv.x; ay += w.y * xv.y; az += w.z * xv.z; aw += w.w * xv.w;
            }
            float s = wave_reduce_sum((ax + ay) + (az + aw));
            if (lane == 0) gi[row] = s + bih[row];
        }
        {
            const float4* Wr = (const float4*)(Whh + (size_t)row * D);
            float ax = 0.f, ay = 0.f, az = 0.f, aw = 0.f;
            #pragma unroll 8
            for (int it = 0; it < 16; ++it) {
                float4 w = Wr[it * 64 + lane];
                float4 xv = xb4[it * 64 + lane];
                ax += w.x * xv.x; ay += w.y * xv.y; az += w.z * xv.z; aw += w.w * xv.w;
            }
            float s = wave_reduce_sum((ax + ay) + (az + aw));
            if (lane == 0) gh[row] = s + bhh[row];
        }
    }
}

// ---------------------------------------------------------------------------
// K6: GRU gate combine (elementwise over D). hidden -> ws and d_out[10:].
// ---------------------------------------------------------------------------
__global__ __launch_bounds__(256)
void gru_combine_kernel(const float* __restrict__ gi, const float* __restrict__ gh,
                        const float* __restrict__ hprev,
                        float* __restrict__ hidden, float* __restrict__ out_hidden) {
    int j = blockIdx.x * 256 + threadIdx.x;
    float r = 1.f / (1.f + expf(-(gi[j] + gh[j])));
    float z = 1.f / (1.f + expf(-(gi[D + j] + gh[D + j])));
    float n = tanhf(gi[2 * D + j] + r * gh[2 * D + j]);
    float h = (1.f - z) * n + z * hprev[j];
    hidden[j] = h;
    out_hidden[j] = h;
}

// ---------------------------------------------------------------------------
// K9: LN+ReLU(t4) -> 10-row GEMV (out_W2) -> agent_feat nonlinearities.
// ---------------------------------------------------------------------------
__global__ __launch_bounds__(1024)
void final_kernel(const float* __restrict__ t4, const float* __restrict__ g,
                  const float* __restrict__ be, const float* __restrict__ W2,
                  const float* __restrict__ b2, float* __restrict__ dout) {
    __shared__ float xs[D];
    __shared__ float red[32];
    __shared__ float out10[10];
    int tid = threadIdx.x, wave = tid >> 6, lane = tid & 63;

    float4 v = ((const float4*)t4)[tid];
    float s1 = (v.x + v.y) + (v.z + v.w);
    float s2 = (v.x * v.x + v.y * v.y) + (v.z * v.z + v.w * v.w);
    s1 = wave_reduce_sum(s1); s2 = wave_reduce_sum(s2);
    if (lane == 0) { red[wave] = s1; red[16 + wave] = s2; }
    __syncthreads();
    float ts1 = 0.f, ts2 = 0.f;
    #pragma unroll
    for (int k = 0; k < 16; ++k) { ts1 += red[k]; ts2 += red[16 + k]; }
    float mu = ts1 * (1.f / 4096.f);
    float rstd = rsqrtf(ts2 * (1.f / 4096.f) - mu * mu + 1e-5f);
    float4 gg = ((const float4*)g)[tid], bb = ((const float4*)be)[tid];
    float4 o;
    o.x = fmaxf((v.x - mu) * rstd * gg.x + bb.x, 0.f);
    o.y = fmaxf((v.y - mu) * rstd * gg.y + bb.y, 0.f);
    o.z = fmaxf((v.z - mu) * rstd * gg.z + bb.z, 0.f);
    o.w = fmaxf((v.w - mu) * rstd * gg.w + bb.w, 0.f);
    ((float4*)xs)[tid] = o;
    __syncthreads();

    if (wave < 10) {
        const float4* Wr = (const float4*)(W2 + (size_t)wave * D);
        const float4* xs4 = (const float4*)xs;
        float ax = 0.f, ay = 0.f, az = 0.f, aw = 0.f;
        #pragma unroll
        for (int it = 0; it < 16; ++it) {
            float4 w = Wr[it * 64 + lane];
            float4 xv = xs4[it * 64 + lane];
            ax += w.x * xv.x; ay += w.y * xv.y; az += w.z * xv.z; aw += w.w * xv.w;
        }
        float s = wave_reduce_sum((ax + ay) + (az + aw));
        if (lane == 0) out10[wave] = s + b2[wave];
    }
    __syncthreads();

    if (tid == 0) {
        dout[0] = out10[0];
        dout[1] = out10[1];
        float nr = sqrtf(out10[2] * out10[2] + out10[3] * out10[3]);
        dout[2] = out10[2] / nr;
        dout[3] = out10[3] / nr;
        #pragma unroll
        for (int k = 4; k < 7; ++k) {
            float x = out10[k];
            dout[k] = fmaxf(x, 0.f) + log1pf(expf(-fabsf(x)));
        }
        float m = fmaxf(out10[7], fmaxf(out10[8], out10[9]));
        float e7 = expf(out10[7] - m), e8 = expf(out10[8] - m), e9 = expf(out10[9] - m);
        float inv = 1.f / (e7 + e8 + e9);
        dout[7] = e7 * inv; dout[8] = e8 * inv; dout[9] = e9 * inv;
    }
}

// ---------------------------------------------------------------------------
extern "C" void kernel_launch(void* const* d_in, const int* in_sizes, int n_in,
                              void* d_out, int out_size, void* d_ws, size_t ws_size,
                              hipStream_t stream) {
    const float* ctx     = (const float*)d_in[0];
    const float* hprev   = (const float*)d_in[1];
    const float* attn    = (const float*)d_in[2];
    const float* paf     = (const float*)d_in[3];
    const float* in_W0   = (const float*)d_in[4];
    const float* in_b0   = (const float*)d_in[5];
    const float* in_g0   = (const float*)d_in[6];
    const float* in_be0  = (const float*)d_in[7];
    const float* in_W1   = (const float*)d_in[8];
    const float* in_b1   = (const float*)d_in[9];
    const float* in_g1   = (const float*)d_in[10];
    const float* in_be1  = (const float*)d_in[11];
    const float* in_W2   = (const float*)d_in[12];
    const float* in_b2   = (const float*)d_in[13];
    const float* gru_Wih = (const float*)d_in[14];
    const float* gru_Whh = (const float*)d_in[15];
    const float* gru_bih = (const float*)d_in[16];
    const float* gru_bhh = (const float*)d_in[17];
    const float* out_W0  = (const float*)d_in[18];
    const float* out_b0  = (const float*)d_in[19];
    const float* out_g0  = (const float*)d_in[20];
    const float* out_be0 = (const float*)d_in[21];
    const float* out_W1  = (const float*)d_in[22];
    const float* out_b1  = (const float*)d_in[23];
    const float* out_g1  = (const float*)d_in[24];
    const float* out_be1 = (const float*)d_in[25];
    const float* out_W2  = (const float*)d_in[26];
    const float* out_b2  = (const float*)d_in[27];

    float* out = (float*)d_out;
    float* ws  = (float*)d_ws;

    float* gin = ws;            // 4160
    float* t0  = ws + 4160;     // 4096
    float* t1  = ws + 8256;     // 4096
    float* gx  = ws + 12352;    // 4096
    float* gi  = ws + 16448;    // 12288
    float* gh  = ws + 28736;    // 12288
    float* hid = ws + 41024;    // 4096
    float* t3  = ws + 45120;    // 4096
    float* t4  = ws + 49216;    // 4096

    prep_kernel<<<1, 1024, 0, stream>>>(attn, ctx, paf, gin);
    // input MLP
    gemv_kernel<DA, false, false, 2><<<512, 256, 0, stream>>>(in_W0, gin, in_b0, nullptr, nullptr, t0);
    gemv_kernel<D,  true,  false, 2><<<512, 256, 0, stream>>>(in_W1, t0, in_b1, in_g0, in_be0, t1);
    gemv_kernel<D,  true,  true,  2><<<512, 256, 0, stream>>>(in_W2, t1, in_b2, in_g1, in_be1, gx);
    // GRU
    gru_gemv_kernel<2><<<1536, 256, 0, stream>>>(gru_Wih, gru_Whh, gx, hprev,
                                                 gru_bih, gru_bhh, gi, gh);
    gru_combine_kernel<<<16, 256, 0, stream>>>(gi, gh, hprev, hid, out + 10);
    // output MLP
    gemv_kernel<D, false, false, 2><<<512, 256, 0, stream>>>(out_W0, hid, out_b0, nullptr, nullptr, t3);
    gemv_kernel<D, true,  false, 2><<<512, 256, 0, stream>>>(out_W1, t3, out_b1, out_g0, out_be0, t4);
    final_kernel<<<1, 1024, 0, stream>>>(t4, out_g1, out_be1, out_W2, out_b2, out);
}

// Round 2
// 638.661 us; speedup vs baseline: 1.0203x; 1.0203x over previous
//
#include <hip/hip_runtime.h>
#include <math.h>

#define D 4096
#define DA 4106   // D + 10 (row length of in_W0)

__device__ __forceinline__ float wave_reduce_sum(float v) {
    #pragma unroll
    for (int off = 32; off > 0; off >>= 1) v += __shfl_xor(v, off, 64);
    return v;
}
__device__ __forceinline__ float wave_reduce_max(float v) {
    #pragma unroll
    for (int off = 32; off > 0; off >>= 1) v = fmaxf(v, __shfl_xor(v, off, 64));
    return v;
}

// ---------------------------------------------------------------------------
// K1: softmax(attn) * context -> gin[0:4096]; prev_agent_feat -> gin[4096:4106]
// ---------------------------------------------------------------------------
__global__ __launch_bounds__(1024)
void prep_kernel(const float* __restrict__ attn, const float* __restrict__ ctx,
                 const float* __restrict__ paf, float* __restrict__ gin) {
    __shared__ float red[16];
    __shared__ float bmax, bsum;
    int tid = threadIdx.x, wave = tid >> 6, lane = tid & 63;

    float4 a = ((const float4*)attn)[tid];
    float mx = fmaxf(fmaxf(a.x, a.y), fmaxf(a.z, a.w));
    mx = wave_reduce_max(mx);
    if (lane == 0) red[wave] = mx;
    __syncthreads();
    if (tid == 0) {
        float m = red[0];
        #pragma unroll
        for (int k = 1; k < 16; ++k) m = fmaxf(m, red[k]);
        bmax = m;
    }
    __syncthreads();
    mx = bmax;

    float e0 = expf(a.x - mx), e1 = expf(a.y - mx), e2 = expf(a.z - mx), e3 = expf(a.w - mx);
    float s = wave_reduce_sum(e0 + e1 + e2 + e3);
    __syncthreads();
    if (lane == 0) red[wave] = s;
    __syncthreads();
    if (tid == 0) {
        float t = 0.f;
        #pragma unroll
        for (int k = 0; k < 16; ++k) t += red[k];
        bsum = t;
    }
    __syncthreads();
    float inv = 1.f / bsum;

    float4 c = ((const float4*)ctx)[tid];
    float4 o;
    o.x = e0 * inv * c.x; o.y = e1 * inv * c.y; o.z = e2 * inv * c.z; o.w = e3 * inv * c.w;
    ((float4*)gin)[tid] = o;
    if (tid < 10) gin[D + tid] = paf[tid];
}

// ---------------------------------------------------------------------------
// One row per 256-thread block GEMV (row length 4096).
// Optional fused LayerNorm+ReLU on the INPUT vector (stats computed in-block
// from the same registers the dot product needs), optional ReLU on output.
// ---------------------------------------------------------------------------
template<bool LN_IN, bool RELU_OUT>
__global__ __launch_bounds__(256, LN_IN ? 6 : 8)
void gemv_row_kernel(const float* __restrict__ W, const float* __restrict__ xin,
                     const float* __restrict__ bias,
                     const float* __restrict__ g, const float* __restrict__ be,
                     float* __restrict__ y) {
    __shared__ float red[8];
    int tid = threadIdx.x, wave = tid >> 6, lane = tid & 63;
    int row = blockIdx.x;

    const float4* x4 = (const float4*)xin;
    float4 xv[4];
    #pragma unroll
    for (int k = 0; k < 4; ++k) xv[k] = x4[k * 256 + tid];

    if constexpr (LN_IN) {
        float s1 = 0.f, s2 = 0.f;
        #pragma unroll
        for (int k = 0; k < 4; ++k) {
            float4 v = xv[k];
            s1 += (v.x + v.y) + (v.z + v.w);
            s2 += (v.x * v.x + v.y * v.y) + (v.z * v.z + v.w * v.w);
        }
        s1 = wave_reduce_sum(s1); s2 = wave_reduce_sum(s2);
        if (lane == 0) { red[wave] = s1; red[4 + wave] = s2; }
        __syncthreads();
        float ts1 = (red[0] + red[1]) + (red[2] + red[3]);
        float ts2 = (red[4] + red[5]) + (red[6] + red[7]);
        float mu = ts1 * (1.f / 4096.f);
        float rstd = rsqrtf(ts2 * (1.f / 4096.f) - mu * mu + 1e-5f);
        #pragma unroll
        for (int k = 0; k < 4; ++k) {
            float4 v = xv[k];
            float4 gg = ((const float4*)g)[k * 256 + tid];
            float4 bb = ((const float4*)be)[k * 256 + tid];
            v.x = fmaxf((v.x - mu) * rstd * gg.x + bb.x, 0.f);
            v.y = fmaxf((v.y - mu) * rstd * gg.y + bb.y, 0.f);
            v.z = fmaxf((v.z - mu) * rstd * gg.z + bb.z, 0.f);
            v.w = fmaxf((v.w - mu) * rstd * gg.w + bb.w, 0.f);
            xv[k] = v;
        }
    }

    const float4* Wr = (const float4*)(W + (size_t)row * D);
    float4 wv[4];
    #pragma unroll
    for (int k = 0; k < 4; ++k) wv[k] = Wr[k * 256 + tid];
    float acc = 0.f;
    #pragma unroll
    for (int k = 0; k < 4; ++k)
        acc += (wv[k].x * xv[k].x + wv[k].y * xv[k].y) +
               (wv[k].z * xv[k].z + wv[k].w * xv[k].w);
    acc = wave_reduce_sum(acc);

    __syncthreads();              // guard red[] reuse (LN path read it above)
    if (lane == 0) red[wave] = acc;
    __syncthreads();
    if (tid == 0) {
        float s = (red[0] + red[1]) + (red[2] + red[3]) + bias[row];
        if (RELU_OUT) s = fmaxf(s, 0.f);
        y[row] = s;
    }
}

// ---------------------------------------------------------------------------
// in_W0 GEMV: rows of length 4106 (only 8B-aligned) -> float2 path.
// One row per 256-thread block. 2053 float2 = 8*256 + 5.
// ---------------------------------------------------------------------------
__global__ __launch_bounds__(256, 8)
void gemv_w0_kernel(const float* __restrict__ W, const float* __restrict__ xin,
                    const float* __restrict__ bias, float* __restrict__ y) {
    __shared__ float red[4];
    int tid = threadIdx.x, wave = tid >> 6, lane = tid & 63;
    int row = blockIdx.x;

    const float2* x2 = (const float2*)xin;
    const float2* Wr = (const float2*)(W + (size_t)row * DA);
    float2 xv[8], wv[8];
    #pragma unroll
    for (int k = 0; k < 8; ++k) { xv[k] = x2[k * 256 + tid]; wv[k] = Wr[k * 256 + tid]; }
    float acc = 0.f;
    #pragma unroll
    for (int k = 0; k < 8; ++k) acc += wv[k].x * xv[k].x + wv[k].y * xv[k].y;
    if (tid < 5) {
        float2 xt = x2[2048 + tid], wt = Wr[2048 + tid];
        acc += wt.x * xt.x + wt.y * xt.y;
    }
    acc = wave_reduce_sum(acc);
    if (lane == 0) red[wave] = acc;
    __syncthreads();
    if (tid == 0) y[row] = (red[0] + red[1]) + (red[2] + red[3]) + bias[row];
}

// ---------------------------------------------------------------------------
// GRU GEMVs, single dispatch: blocks [0,12288) -> Wih@xa rows, [12288,24576)
// -> Whh@xb rows. One row per block.
// ---------------------------------------------------------------------------
__global__ __launch_bounds__(256, 8)
void gru_gemv_kernel(const float* __restrict__ Wih, const float* __restrict__ Whh,
                     const float* __restrict__ xa, const float* __restrict__ xb,
                     const float* __restrict__ bih, const float* __restrict__ bhh,
                     float* __restrict__ gi, float* __restrict__ gh) {
    __shared__ float red[4];
    int b = blockIdx.x;
    int tid = threadIdx.x, wave = tid >> 6, lane = tid & 63;
    const float* W; const float* x; const float* bias; float* y; int row;
    if (b < 12288) { W = Wih; x = xa; bias = bih; y = gi; row = b; }
    else           { W = Whh; x = xb; bias = bhh; y = gh; row = b - 12288; }

    const float4* x4 = (const float4*)x;
    const float4* Wr = (const float4*)(W + (size_t)row * D);
    float4 xv[4], wv[4];
    #pragma unroll
    for (int k = 0; k < 4; ++k) { xv[k] = x4[k * 256 + tid]; wv[k] = Wr[k * 256 + tid]; }
    float acc = 0.f;
    #pragma unroll
    for (int k = 0; k < 4; ++k)
        acc += (wv[k].x * xv[k].x + wv[k].y * xv[k].y) +
               (wv[k].z * xv[k].z + wv[k].w * xv[k].w);
    acc = wave_reduce_sum(acc);
    if (lane == 0) red[wave] = acc;
    __syncthreads();
    if (tid == 0) y[row] = (red[0] + red[1]) + (red[2] + red[3]) + bias[row];
}

// ---------------------------------------------------------------------------
// GRU gate combine (elementwise over D). hidden -> ws and d_out[10:].
// ---------------------------------------------------------------------------
__global__ __launch_bounds__(256)
void gru_combine_kernel(const float* __restrict__ gi, const float* __restrict__ gh,
                        const float* __restrict__ hprev,
                        float* __restrict__ hidden, float* __restrict__ out_hidden) {
    int j = blockIdx.x * 256 + threadIdx.x;
    float r = 1.f / (1.f + expf(-(gi[j] + gh[j])));
    float z = 1.f / (1.f + expf(-(gi[D + j] + gh[D + j])));
    float n = tanhf(gi[2 * D + j] + r * gh[2 * D + j]);
    float h = (1.f - z) * n + z * hprev[j];
    hidden[j] = h;
    out_hidden[j] = h;
}

// ---------------------------------------------------------------------------
// K9: LN+ReLU(t4) -> 10-row GEMV (out_W2) -> agent_feat nonlinearities.
// ---------------------------------------------------------------------------
__global__ __launch_bounds__(1024)
void final_kernel(const float* __restrict__ t4, const float* __restrict__ g,
                  const float* __restrict__ be, const float* __restrict__ W2,
                  const float* __restrict__ b2, float* __restrict__ dout) {
    __shared__ float xs[D];
    __shared__ float red[32];
    __shared__ float out10[10];
    int tid = threadIdx.x, wave = tid >> 6, lane = tid & 63;

    float4 v = ((const float4*)t4)[tid];
    float s1 = (v.x + v.y) + (v.z + v.w);
    float s2 = (v.x * v.x + v.y * v.y) + (v.z * v.z + v.w * v.w);
    s1 = wave_reduce_sum(s1); s2 = wave_reduce_sum(s2);
    if (lane == 0) { red[wave] = s1; red[16 + wave] = s2; }
    __syncthreads();
    float ts1 = 0.f, ts2 = 0.f;
    #pragma unroll
    for (int k = 0; k < 16; ++k) { ts1 += red[k]; ts2 += red[16 + k]; }
    float mu = ts1 * (1.f / 4096.f);
    float rstd = rsqrtf(ts2 * (1.f / 4096.f) - mu * mu + 1e-5f);
    float4 gg = ((const float4*)g)[tid], bb = ((const float4*)be)[tid];
    float4 o;
    o.x = fmaxf((v.x - mu) * rstd * gg.x + bb.x, 0.f);
    o.y = fmaxf((v.y - mu) * rstd * gg.y + bb.y, 0.f);
    o.z = fmaxf((v.z - mu) * rstd * gg.z + bb.z, 0.f);
    o.w = fmaxf((v.w - mu) * rstd * gg.w + bb.w, 0.f);
    ((float4*)xs)[tid] = o;
    __syncthreads();

    if (wave < 10) {
        const float4* Wr = (const float4*)(W2 + (size_t)wave * D);
        const float4* xs4 = (const float4*)xs;
        float ax = 0.f, ay = 0.f, az = 0.f, aw = 0.f;
        #pragma unroll
        for (int it = 0; it < 16; ++it) {
            float4 w = Wr[it * 64 + lane];
            float4 xv = xs4[it * 64 + lane];
            ax += w.x * xv.x; ay += w.y * xv.y; az += w.z * xv.z; aw += w.w * xv.w;
        }
        float s = wave_reduce_sum((ax + ay) + (az + aw));
        if (lane == 0) out10[wave] = s + b2[wave];
    }
    __syncthreads();

    if (tid == 0) {
        dout[0] = out10[0];
        dout[1] = out10[1];
        float nr = sqrtf(out10[2] * out10[2] + out10[3] * out10[3]);
        dout[2] = out10[2] / nr;
        dout[3] = out10[3] / nr;
        #pragma unroll
        for (int k = 4; k < 7; ++k) {
            float x = out10[k];
            dout[k] = fmaxf(x, 0.f) + log1pf(expf(-fabsf(x)));
        }
        float m = fmaxf(out10[7], fmaxf(out10[8], out10[9]));
        float e7 = expf(out10[7] - m), e8 = expf(out10[8] - m), e9 = expf(out10[9] - m);
        float inv = 1.f / (e7 + e8 + e9);
        dout[7] = e7 * inv; dout[8] = e8 * inv; dout[9] = e9 * inv;
    }
}

// ---------------------------------------------------------------------------
extern "C" void kernel_launch(void* const* d_in, const int* in_sizes, int n_in,
                              void* d_out, int out_size, void* d_ws, size_t ws_size,
                              hipStream_t stream) {
    const float* ctx     = (const float*)d_in[0];
    const float* hprev   = (const float*)d_in[1];
    const float* attn    = (const float*)d_in[2];
    const float* paf     = (const float*)d_in[3];
    const float* in_W0   = (const float*)d_in[4];
    const float* in_b0   = (const float*)d_in[5];
    const float* in_g0   = (const float*)d_in[6];
    const float* in_be0  = (const float*)d_in[7];
    const float* in_W1   = (const float*)d_in[8];
    const float* in_b1   = (const float*)d_in[9];
    const float* in_g1   = (const float*)d_in[10];
    const float* in_be1  = (const float*)d_in[11];
    const float* in_W2   = (const float*)d_in[12];
    const float* in_b2   = (const float*)d_in[13];
    const float* gru_Wih = (const float*)d_in[14];
    const float* gru_Whh = (const float*)d_in[15];
    const float* gru_bih = (const float*)d_in[16];
    const float* gru_bhh = (const float*)d_in[17];
    const float* out_W0  = (const float*)d_in[18];
    const float* out_b0  = (const float*)d_in[19];
    const float* out_g0  = (const float*)d_in[20];
    const float* out_be0 = (const float*)d_in[21];
    const float* out_W1  = (const float*)d_in[22];
    const float* out_b1  = (const float*)d_in[23];
    const float* out_g1  = (const float*)d_in[24];
    const float* out_be1 = (const float*)d_in[25];
    const float* out_W2  = (const float*)d_in[26];
    const float* out_b2  = (const float*)d_in[27];

    float* out = (float*)d_out;
    float* ws  = (float*)d_ws;

    float* gin = ws;            // 4160
    float* t0  = ws + 4160;     // 4096
    float* t1  = ws + 8256;     // 4096
    float* gx  = ws + 12352;    // 4096
    float* gi  = ws + 16448;    // 12288
    float* gh  = ws + 28736;    // 12288
    float* hid = ws + 41024;    // 4096
    float* t3  = ws + 45120;    // 4096
    float* t4  = ws + 49216;    // 4096

    prep_kernel<<<1, 1024, 0, stream>>>(attn, ctx, paf, gin);
    // input MLP
    gemv_w0_kernel<<<4096, 256, 0, stream>>>(in_W0, gin, in_b0, t0);
    gemv_row_kernel<true,  false><<<4096, 256, 0, stream>>>(in_W1, t0, in_b1, in_g0, in_be0, t1);
    gemv_row_kernel<true,  true ><<<4096, 256, 0, stream>>>(in_W2, t1, in_b2, in_g1, in_be1, gx);
    // GRU (both matrices in one dispatch)
    gru_gemv_kernel<<<24576, 256, 0, stream>>>(gru_Wih, gru_Whh, gx, hprev,
                                               gru_bih, gru_bhh, gi, gh);
    gru_combine_kernel<<<16, 256, 0, stream>>>(gi, gh, hprev, hid, out + 10);
    // output MLP
    gemv_row_kernel<false, false><<<4096, 256, 0, stream>>>(out_W0, hid, out_b0, nullptr, nullptr, t3);
    gemv_row_kernel<true,  false><<<4096, 256, 0, stream>>>(out_W1, t3, out_b1, out_g0, out_be0, t4);
    final_kernel<<<1, 1024, 0, stream>>>(t4, out_g1, out_be1, out_W2, out_b2, out);
}